// Round 1
// baseline (920.540 us; speedup 1.0000x reference)
//
#include <hip/hip_runtime.h>

// Problem constants: flow/flowback [B,2,T,H,W] fp32, masks [B,1,T,H,W] fp32.
#define BB 8
#define CC 2
#define TT 8
#define HH 512
#define WW 512
#define HWSZ (HH * WW)                    // 262144
#define TOTAL_PIX (BB * TT * HWSZ)        // 16,777,216  (b,t,y,x)
#define TOTAL_ELEMS ((double)(BB * CC * TT) * (double)HWSZ)  // 33,554,432 (mean denom)

// Bilinear sample of a 2-channel image (channel planes c0, c1; each HxW),
// zeros padding, align_corners=True semantics (pixel-space coords).
__device__ __forceinline__ float2 bilin2(const float* __restrict__ c0,
                                         const float* __restrict__ c1,
                                         float sx, float sy)
{
    float x0f = floorf(sx);
    float y0f = floorf(sy);
    float wx1 = sx - x0f;
    float wy1 = sy - y0f;
    int x0 = (int)x0f;
    int y0 = (int)y0f;
    int x1 = x0 + 1;
    int y1 = y0 + 1;

    float vx0 = (x0 >= 0 && x0 < WW) ? 1.f : 0.f;
    float vx1 = (x1 >= 0 && x1 < WW) ? 1.f : 0.f;
    float vy0 = (y0 >= 0 && y0 < HH) ? 1.f : 0.f;
    float vy1 = (y1 >= 0 && y1 < HH) ? 1.f : 0.f;

    int xc0 = min(max(x0, 0), WW - 1);
    int xc1 = min(max(x1, 0), WW - 1);
    int yc0 = min(max(y0, 0), HH - 1);
    int yc1 = min(max(y1, 0), HH - 1);

    float w00 = (1.f - wx1) * (1.f - wy1) * vx0 * vy0;
    float w10 = wx1         * (1.f - wy1) * vx1 * vy0;
    float w01 = (1.f - wx1) * wy1         * vx0 * vy1;
    float w11 = wx1         * wy1         * vx1 * vy1;

    int o00 = yc0 * WW + xc0;
    int o10 = yc0 * WW + xc1;
    int o01 = yc1 * WW + xc0;
    int o11 = yc1 * WW + xc1;

    float r0 = w00 * c0[o00] + w10 * c0[o10] + w01 * c0[o01] + w11 * c0[o11];
    float r1 = w00 * c1[o00] + w10 * c1[o10] + w01 * c1[o01] + w11 * c1[o11];
    return make_float2(r0, r1);
}

__global__ __launch_bounds__(256) void flow_loss_kernel(
    const float* __restrict__ flow,
    const float* __restrict__ flowback,
    const float* __restrict__ mask_fw,
    const float* __restrict__ mask_bw,
    double* __restrict__ acc)
{
    const int stride = gridDim.x * blockDim.x;
    float lsum = 0.f;

    for (int idx = blockIdx.x * blockDim.x + threadIdx.x; idx < TOTAL_PIX; idx += stride) {
        int pix = idx & (HWSZ - 1);   // y*W + x within the (b,t) slice
        int x   = pix & (WW - 1);
        int y   = pix >> 9;           // W == 512
        int bt  = idx >> 18;          // HWSZ == 2^18; bt = b*T + t
        int b   = bt >> 3;            // T == 8
        int t   = bt & 7;

        // [B,C,T,H,W]: slice(b,c,t) offset = ((b*2 + c)*8 + t) * HWSZ
        int fs0 = (b * 16 + t) * HWSZ;     // channel 0 plane
        int fs1 = fs0 + 8 * HWSZ;          // channel 1 plane
        const float* f0 = flow + fs0;
        const float* f1 = flow + fs1;
        const float* g0 = flowback + fs0;
        const float* g1 = flowback + fs1;

        float fx = f0[pix];
        float fy = f1[pix];
        float gx = g0[pix];
        float gy = g1[pix];
        // masks are [B,1,T,H,W] -> flat index == idx exactly
        float mf = mask_fw[idx];
        float mb = mask_bw[idx];

        // nextloss term: warp(flowback, flow) + flow
        float2 wfb = bilin2(g0, g1, (float)x + fx, (float)y + fy);
        // prevloss term: warp(flow, flowback) + flowback
        float2 wf  = bilin2(f0, f1, (float)x + gx, (float)y + gy);

        lsum += mf * (fabsf(wfb.x + fx) + fabsf(wfb.y + fy))
              + mb * (fabsf(wf.x + gx) + fabsf(wf.y + gy));
    }

    // wave64 reduce
    for (int off = 32; off > 0; off >>= 1)
        lsum += __shfl_down(lsum, off, 64);

    __shared__ float wsum[4];
    int lane = threadIdx.x & 63;
    int wv   = threadIdx.x >> 6;
    if (lane == 0) wsum[wv] = lsum;
    __syncthreads();
    if (threadIdx.x == 0) {
        float s = wsum[0] + wsum[1] + wsum[2] + wsum[3];
        atomicAdd(acc, (double)s);
    }
}

__global__ void finalize_kernel(const double* __restrict__ acc,
                                const int* __restrict__ npf,
                                float* __restrict__ out)
{
    out[0] = (float)(acc[0] * ((double)npf[0] / TOTAL_ELEMS));
}

extern "C" void kernel_launch(void* const* d_in, const int* in_sizes, int n_in,
                              void* d_out, int out_size, void* d_ws, size_t ws_size,
                              hipStream_t stream)
{
    const float* flow     = (const float*)d_in[0];
    const float* flowback = (const float*)d_in[1];
    const float* mask_fw  = (const float*)d_in[2];
    const float* mask_bw  = (const float*)d_in[3];
    const int*   npf      = (const int*)d_in[4];
    float*  out = (float*)d_out;
    double* acc = (double*)d_ws;

    // zero the accumulator (d_ws is poisoned before every timed launch)
    hipMemsetAsync(d_ws, 0, sizeof(double), stream);

    flow_loss_kernel<<<4096, 256, 0, stream>>>(flow, flowback, mask_fw, mask_bw, acc);
    finalize_kernel<<<1, 1, 0, stream>>>(acc, npf, out);
}